// Round 12
// baseline (113.882 us; speedup 1.0000x reference)
//
#include <hip/hip_runtime.h>
#include <hip/hip_bf16.h>

// Problem constants
static constexpr int Bn = 8, Cn = 128, Hn = 64, Wn = 64, Con = 128;
static constexpr int KKn = 9, DGn = 2, Cgn = 64;
static constexpr int HOn = 64, WOn = 64;
static constexpr int PITCH = 72;     // bf16 row pitch for s_val rows
static constexpr int OMP3 = 66;      // s_om row pitch (shorts), 64 pos + pad

typedef short short8 __attribute__((ext_vector_type(8)));
typedef float f32x4  __attribute__((ext_vector_type(4)));

__device__ __forceinline__ unsigned short f2bf(float f) {
    unsigned u = __float_as_uint(f);
    u += 0x7fff + ((u >> 16) & 1);          // round-to-nearest-even
    return (unsigned short)(u >> 16);
}
__device__ __forceinline__ float bf2f(unsigned short h) {
    return __uint_as_float(((unsigned)h) << 16);
}

// ---------------------------------------------------------------------------
// Kernel P (R18, proven): WEIGHTS-ONLY prep.
// Blocks [0,576):   main weight -> MFMA B-frag order wt2[gk][ks][tile][lane][8].
// Blocks [576,720): offset weight -> owf[g][ks=tap*2+ch][nt][lane][8].
// ---------------------------------------------------------------------------
__global__ __launch_bounds__(256) void prep(const float* __restrict__ w,
                                            const float* __restrict__ ow,
                                            unsigned short* __restrict__ wt2,
                                            unsigned short* __restrict__ owf) {
    const int blk = blockIdx.x;
    const int t = threadIdx.x;
    if (blk < 576) {
        int e    = blk * 256 + t;                // [0,147456)
        int j    = e & 7;
        int lane = (e >> 3) & 63;
        int tile = (e >> 9) & 7;
        int ks   = (e >> 12) & 1;
        int gk   = e >> 13;                      // 0..17
        int g = gk / 9, k = gk - g * 9;
        int oc = tile * 16 + (lane & 15);
        int c  = ks * 32 + (lane >> 4) * 8 + j;
        wt2[e] = f2bf(w[((size_t)oc * Cn + g * Cgn + c) * KKn + k]);
    } else {
        int e = (blk - 576) * 256 + t;           // [0,36864)
        int g  = e / 18432;
        int r  = e - g * 18432;
        int ks = r >> 10;
        int r2 = r & 1023;
        int nt = r2 >> 9;
        int lane = (r2 >> 3) & 63;
        int j  = r2 & 7;
        int tap = ks >> 1, chalf = ks & 1;
        int oc_l = nt * 16 + (lane & 15);
        int c = chalf * 32 + (lane >> 4) * 8 + j;
        float v = 0.f;
        if (oc_l < 27)
            v = ow[((size_t)(g * 27 + oc_l) * Cgn + c) * KKn + tap];
        owf[e] = f2bf(v);
    }
}

// ---------------------------------------------------------------------------
// Kernel 2 (R20): R18 EXACT math (R19 asm diet reverted per m240 lesson)
// + producer REGISTER PIPELINE.
// R18 critical chain per round: cw/pk LDS read -> 4 dependent s_xw ds_reads
// -> bilinear -> write, all inside one barrier interval (~500cy exposed).
// s_xw/s_cw/s_pk are READ-ONLY during P2, so the producer prefetches the
// NEXT tile's {cw, corners} into registers one round ahead: post-barrier it
// starts bilinear immediately (0 LDS latency on the critical path); the
// prefetch for gk+2 issues after and its latency hides under consumer MFMA.
// Consumer/stage/P0/P1: R18 verbatim. Output bit-identical.
// LDS: 114688 (s_xw) + 18432 (s_val dbuf, s_om aliased) + 18432 (s_cw)
//      + 4608 (s_pk) = 156160 B -> 1 block/CU, 16 waves.
// ---------------------------------------------------------------------------
__global__ __launch_bounds__(1024, 4) void dcn_fused(const float* __restrict__ x,
                                                     const unsigned short* __restrict__ owf,
                                                     const float* __restrict__ ob,
                                                     const unsigned short* __restrict__ wt2,
                                                     float* __restrict__ out) {
    __shared__ __align__(16) unsigned short s_xw[7 * 64 * 16 * 8];   // 114688 B window
    __shared__ __align__(16) unsigned short s_val[2][64 * PITCH];    // 18432 B dbuf
    __shared__ float4 s_cw[18][64];                                  // 18432 B
    __shared__ int    s_pk[18][64];                                  // 4608 B

    unsigned short* s_om = &s_val[0][0];     // alias: s_om (7128 B) lives pre-P2

    const int t  = threadIdx.x;              // [0,1024)
    const int id = blockIdx.x;               // [0,512)
    const int b  = id & 7;                   // XCD-aware: batch b -> XCD b
    const int ho = id >> 3;                  // full output row

    const int lane = t & 63;
    const int wv   = t >> 6;                 // wave id 0..15
    const int lr   = lane & 15;              // MFMA row/col part
    const int lk   = (lane >> 4) * 8;        // MFMA k offset (shorts)
    const int q    = lane >> 4;              // D row quad

    const int lo = max(0, ho - 3);
    const int hi = min(Hn - 1, ho + 3);
    const int nrows = hi - lo + 1;           // <= 7

    const float* xb4 = x + (size_t)b * Cn * Hn * Wn;   // NCHW batch base
    const short8 zz = {0, 0, 0, 0, 0, 0, 0, 0};

    // ---- S: stage x window rows [lo,hi] into LDS, transposing on the fly ----
    for (int u = t; u < nrows * 1024; u += 1024) {
        int xx = u & 63;
        int kk = (u >> 6) & 15;
        int rs = u >> 10;
        int y  = lo + rs;
        short8 v;
#pragma unroll
        for (int j = 0; j < 8; ++j) {
            float f = xb4[(((size_t)(kk * 8 + j) * Hn) + y) * Wn + xx];
            v[j] = (short)f2bf(f);
        }
        *(short8*)&s_xw[(((rs * 64 + xx) * 16) + (kk ^ (xx & 15))) * 8] = v;
    }
    __syncthreads();

    // ---- P0: offset-conv GEMM on ALL 16 waves, A from LDS window ----
    {
        const int cg = wv >> 3;              // conv/deform group
        const int rh4 = (wv >> 1) & 3;       // row quarter (pos base rh4*16)
        const int nh = wv & 1;               // oc 16-block
        const int oc_l = nh * 16 + lr;
        float bias = (oc_l < 27) ? ob[cg * 27 + oc_l] : 0.f;
        f32x4 oacc = (f32x4){bias, bias, bias, bias};

        const unsigned short* wf = owf + (size_t)cg * 18432;

        for (int tap = 0; tap < 9; ++tap) {
            int ky = tap / 3, kx = tap - ky * 3;
            int y = ho - 2 + 2 * ky;
            if (y < 0 || y >= Hn) continue;  // wave-uniform skip (zero pad)
            int slot = y - lo;               // y in [lo,hi] guaranteed
#pragma unroll
            for (int ch = 0; ch < 2; ++ch) {
                int kssl = tap * 2 + ch;
                short8 bv = *(const short8*)&wf[(size_t)kssl * 1024 + nh * 512 + lane * 8];
                int wo = rh4 * 16 + lr;
                int xc = wo - 2 + 2 * kx;
                bool vx = (xc >= 0) & (xc < Wn);
                int xcc = min(max(xc, 0), Wn - 1);
                int kk  = (cg * 8 + ch * 4 + (lane >> 4)) ^ (xcc & 15);
                short8 av = *(const short8*)&s_xw[(((slot * 64 + xcc) * 16) + kk) * 8];
                av = vx ? av : zz;
                oacc = __builtin_amdgcn_mfma_f32_16x16x32_bf16(av, bv, oacc, 0, 0, 0);
            }
        }
        if (oc_l < 27) {
            int c54 = cg * 27 + oc_l;
#pragma unroll
            for (int r = 0; r < 4; ++r)
                s_om[c54 * OMP3 + rh4 * 16 + q * 4 + r] = f2bf(oacc[r]);
        }
    }
    __syncthreads();

    // ---- P1: sampling params for all (gk, pos) of this row ----
    for (int e = t; e < 18 * 64; e += 1024) {
        int pos = e & 63;
        int wo  = pos;
        int gk  = e >> 6;
        int g  = gk / 9, k = gk - g * 9;
        int ky = k / 3,  kx = k - ky * 3;
        float offy = bf2f(s_om[(g * 18 + k * 2 + 0) * OMP3 + pos]);
        float offx = bf2f(s_om[(g * 18 + k * 2 + 1) * OMP3 + pos]);
        float mk   = bf2f(s_om[(36 + g * 9 + k) * OMP3 + pos]);
        mk = 2.0f / (1.0f + __expf(-mk));

        float py = offy + (float)(ky * 2 + ho - 2);
        float px = offx + (float)(kx * 2 + wo - 2);
        float fy = floorf(py), fx = floorf(px);
        int   y0 = (int)fy,    x0 = (int)fx;
        float wy = py - fy,    wx = px - fx;

        bool vy0 = (y0 >= 0) & (y0 < Hn);
        bool vy1 = (y0 + 1 >= 0) & (y0 + 1 < Hn);
        bool vx0 = (x0 >= 0) & (x0 < Wn);
        bool vx1 = (x0 + 1 >= 0) & (x0 + 1 < Wn);
        float4 cw;
        cw.x = (vy0 & vx0) ? (1.f - wy) * (1.f - wx) * mk : 0.f;
        cw.y = (vy0 & vx1) ? (1.f - wy) * wx * mk : 0.f;
        cw.z = (vy1 & vx0) ? wy * (1.f - wx) * mk : 0.f;
        cw.w = (vy1 & vx1) ? wy * wx * mk : 0.f;

        int y0c = min(max(y0, 0), Hn - 1);
        int y1c = min(max(y0 + 1, 0), Hn - 1);
        int x0c = min(max(x0, 0), Wn - 1);
        int x1c = min(max(x0 + 1, 0), Wn - 1);
        s_cw[gk][pos] = cw;
        s_pk[gk][pos] = y0c | (y1c << 8) | (x0c << 16) | (x1c << 24);
    }
    __syncthreads();   // also fences s_om -> s_val reuse

    // ---- P2: producer/consumer gk loop with producer register pipeline ----
    const int pos = t >> 3;                  // producer: position 0..63
    const int c8  = t & 7;                   // producer: 8-ch chunk id

    // producer pipeline state (next tile's cw + corners in registers)
    float4 cwA;
    short8 a00A, a01A, a10A, a11A;

    // load_state(gkj): fetch cw/pk then corners (LDS window or rare global
    // fallback) into the named state registers. R18 math verbatim.
    auto load_state = [&](int gkj) {
        const int g = (gkj >= 9) ? 1 : 0;
        cwA = s_cw[gkj][pos];
        int pk  = s_pk[gkj][pos];
        int y0c = pk & 255, y1c = (pk >> 8) & 255;
        int x0c = (pk >> 16) & 255, x1c = (pk >> 24) & 255;
        bool ok = (y0c >= lo) & (y1c <= hi);
        if (__all(ok)) {
            const int kg = g * 8 + c8;
            a00A = *(const short8*)&s_xw[((((y0c - lo) * 64 + x0c) * 16) + (kg ^ (x0c & 15))) * 8];
            a01A = *(const short8*)&s_xw[((((y0c - lo) * 64 + x1c) * 16) + (kg ^ (x1c & 15))) * 8];
            a10A = *(const short8*)&s_xw[((((y1c - lo) * 64 + x0c) * 16) + (kg ^ (x0c & 15))) * 8];
            a11A = *(const short8*)&s_xw[((((y1c - lo) * 64 + x1c) * 16) + (kg ^ (x1c & 15))) * 8];
        } else {
            const float* xc0 = xb4 + (size_t)(g * Cgn + c8 * 8) * Hn * Wn;
#pragma unroll
            for (int j = 0; j < 8; ++j) {
                const float* xj = xc0 + (size_t)j * Hn * Wn;
                a00A[j] = (short)f2bf(xj[(size_t)y0c * Wn + x0c]);
                a01A[j] = (short)f2bf(xj[(size_t)y0c * Wn + x1c]);
                a10A[j] = (short)f2bf(xj[(size_t)y1c * Wn + x0c]);
                a11A[j] = (short)f2bf(xj[(size_t)y1c * Wn + x1c]);
            }
        }
    };

    // bilinear on the state regs, write to s_val[buf] (R18 math verbatim)
    auto emit_tile = [&](int buf) {
        short8 h0;
#pragma unroll
        for (int i = 0; i < 8; ++i) {
            float v = cwA.x * bf2f((unsigned short)a00A[i]) +
                      cwA.y * bf2f((unsigned short)a01A[i]) +
                      cwA.z * bf2f((unsigned short)a10A[i]) +
                      cwA.w * bf2f((unsigned short)a11A[i]);
            h0[i] = (short)f2bf(v);
        }
        *(short8*)&s_val[buf][pos * PITCH + c8 * 8] = h0;
    };

    f32x4 acc[2][2];                         // [i = mt in pair][j = oc-16 in pair]
#pragma unroll
    for (int i = 0; i < 2; ++i)
#pragma unroll
        for (int j = 0; j < 2; ++j) acc[i][j] = (f32x4){0.f, 0.f, 0.f, 0.f};

    if (wv < 8) {
        load_state(0);
        emit_tile(0);                        // prologue: buf0 = gk 0
        load_state(1);                       // prefetch gk 1
    }

    const int cid = wv - 8;                  // consumer id 0..7 (wv >= 8)
    const int rh2 = cid >> 2;                // mt pair: rows (rh2*2+i)*16
    const int nt2 = cid & 3;                 // oc-32: tiles nt2*2 + j

    for (int gk = 0; gk < 18; ++gk) {
        __syncthreads();                     // s_val[gk&1] ready for consumers
        if (wv < 8) {
            if (gk < 17) {
                emit_tile((gk + 1) & 1);     // corners already in regs: no LDS
                                             // latency on the critical path
                if (gk < 16) load_state(gk + 2);   // prefetch; latency hides
            }
        } else {
            const unsigned short* wf = wt2 + (size_t)gk * 8192;
#pragma unroll
            for (int ks = 0; ks < 2; ++ks) {
                short8 af[2];
#pragma unroll
                for (int i = 0; i < 2; ++i)
                    af[i] = *(const short8*)&s_val[gk & 1][((rh2 * 2 + i) * 16 + lr) * PITCH + ks * 32 + lk];
#pragma unroll
                for (int i = 0; i < 2; ++i)
#pragma unroll
                    for (int j = 0; j < 2; ++j) {
                        short8 bfr = *(const short8*)&wf[(size_t)(ks * 8 + nt2 * 2 + j) * 512 + lane * 8];
                        acc[i][j] = __builtin_amdgcn_mfma_f32_16x16x32_bf16(af[i], bfr, acc[i][j], 0, 0, 0);
                    }
            }
        }
    }

    // ---- epilogue (consumers): oc = (nt2*2+j)*16 + lr; rows (rh2*2+i)*16 + q*4 ----
    if (wv >= 8) {
#pragma unroll
        for (int i = 0; i < 2; ++i)
#pragma unroll
            for (int j = 0; j < 2; ++j) {
                int oc = (nt2 * 2 + j) * 16 + lr;
                int p0 = (rh2 * 2 + i) * 16 + q * 4;
                float4 v = {acc[i][j][0], acc[i][j][1], acc[i][j][2], acc[i][j][3]};
                *(float4*)&out[(((size_t)b * Con + oc) * HOn + ho) * WOn + p0] = v;
            }
    }
}

// ---------------------------------------------------------------------------
extern "C" void kernel_launch(void* const* d_in, const int* in_sizes, int n_in,
                              void* d_out, int out_size, void* d_ws, size_t ws_size,
                              hipStream_t stream) {
    const float* x  = (const float*)d_in[0];   // [8,128,64,64]
    const float* ow = (const float*)d_in[1];   // [54,64,3,3]
    const float* ob = (const float*)d_in[2];   // [54]
    const float* w  = (const float*)d_in[3];   // [128,128,3,3]
    float* out = (float*)d_out;                // [8,128,64,64]

    // ws: wt2 294,912 | owf 73,728
    unsigned short* wt2 = (unsigned short*)d_ws;
    unsigned short* owf = (unsigned short*)((char*)d_ws + 294912);

    hipLaunchKernelGGL(prep, dim3(720), dim3(256), 0, stream,
                       w, ow, wt2, owf);
    hipLaunchKernelGGL(dcn_fused, dim3(512), dim3(1024), 0, stream,
                       x, owf, ob, wt2, out);
}

// Round 13
// 113.563 us; speedup vs baseline: 1.0028x; 1.0028x over previous
//
#include <hip/hip_runtime.h>
#include <hip/hip_bf16.h>

// Problem constants
static constexpr int Bn = 8, Cn = 128, Hn = 64, Wn = 64, Con = 128;
static constexpr int KKn = 9, DGn = 2, Cgn = 64;
static constexpr int HOn = 64, WOn = 64;
static constexpr int PITCH = 72;     // bf16 row pitch for s_val rows
static constexpr int OMP3 = 66;      // s_om row pitch (shorts), 64 pos + pad

typedef short short8 __attribute__((ext_vector_type(8)));
typedef float f32x4  __attribute__((ext_vector_type(4)));

__device__ __forceinline__ unsigned short f2bf(float f) {
    unsigned u = __float_as_uint(f);
    u += 0x7fff + ((u >> 16) & 1);          // round-to-nearest-even
    return (unsigned short)(u >> 16);
}
__device__ __forceinline__ float bf2f(unsigned short h) {
    return __uint_as_float(((unsigned)h) << 16);
}

// Barrier WITHOUT the compiler's vmcnt(0) drain: LDS ops visible (each wave
// drains its own lgkm before the barrier), but in-flight global loads ride
// across (T4). sched_barrier(0) per guide rule #18.
#define BARRIER_NODRAIN()                                        \
    do {                                                         \
        asm volatile("s_waitcnt lgkmcnt(0)" ::: "memory");       \
        __builtin_amdgcn_s_barrier();                            \
        __builtin_amdgcn_sched_barrier(0);                       \
    } while (0)

// ---------------------------------------------------------------------------
// Kernel P (R18, proven): WEIGHTS-ONLY prep.
// Blocks [0,576):   main weight -> MFMA B-frag order wt2[gk][ks][tile][lane][8].
// Blocks [576,720): offset weight -> owf[g][ks=tap*2+ch][nt][lane][8].
// ---------------------------------------------------------------------------
__global__ __launch_bounds__(256) void prep(const float* __restrict__ w,
                                            const float* __restrict__ ow,
                                            unsigned short* __restrict__ wt2,
                                            unsigned short* __restrict__ owf) {
    const int blk = blockIdx.x;
    const int t = threadIdx.x;
    if (blk < 576) {
        int e    = blk * 256 + t;                // [0,147456)
        int j    = e & 7;
        int lane = (e >> 3) & 63;
        int tile = (e >> 9) & 7;
        int ks   = (e >> 12) & 1;
        int gk   = e >> 13;                      // 0..17
        int g = gk / 9, k = gk - g * 9;
        int oc = tile * 16 + (lane & 15);
        int c  = ks * 32 + (lane >> 4) * 8 + j;
        wt2[e] = f2bf(w[((size_t)oc * Cn + g * Cgn + c) * KKn + k]);
    } else {
        int e = (blk - 576) * 256 + t;           // [0,36864)
        int g  = e / 18432;
        int r  = e - g * 18432;
        int ks = r >> 10;
        int r2 = r & 1023;
        int nt = r2 >> 9;
        int lane = (r2 >> 3) & 63;
        int j  = r2 & 7;
        int tap = ks >> 1, chalf = ks & 1;
        int oc_l = nt * 16 + (lane & 15);
        int c = chalf * 32 + (lane >> 4) * 8 + j;
        float v = 0.f;
        if (oc_l < 27)
            v = ow[((size_t)(g * 27 + oc_l) * Cgn + c) * KKn + tap];
        owf[e] = f2bf(v);
    }
}

// ---------------------------------------------------------------------------
// Kernel 2 (R21): R18 exact math + ENFORCED latency pipeline in P2.
// R20's pipeline was silently defeated (VGPR 52 unchanged -> compiler sank
// the prefetches). R21 pins it structurally:
//   - BARRIER_NODRAIN in the P2 loop: consumer B-frag global loads ride
//     across barriers (plain __syncthreads drains vmcnt(0) and re-exposes
//     ~250cy/gk).
//   - Consumer: prefetch gk+1's 4 B-frags right after the barrier, then
//     sched_barrier(0) (loads cannot sink), then af ds_reads + 8 MFMA on the
//     RESIDENT bfrA regs, then rotate.
//   - Producer: register state {cw, 4 corners} one tile ahead; emit_tile
//     post-barrier has zero LDS latency on the critical path; load_state
//     for gk+2 issues after, hidden under the interval. The barrier macro's
//     "memory"-clobber asm fences keep the ds_reads where written.
// Race proof (same as R10/R18): each wave drains its own LDS ops pre-barrier;
// buffer X written in interval i is read in i+1 and rewritten in i+2.
// Output bit-identical to R18. LDS: 156160 B -> 1 block/CU, 16 waves.
// ---------------------------------------------------------------------------
__global__ __launch_bounds__(1024, 4) void dcn_fused(const float* __restrict__ x,
                                                     const unsigned short* __restrict__ owf,
                                                     const float* __restrict__ ob,
                                                     const unsigned short* __restrict__ wt2,
                                                     float* __restrict__ out) {
    __shared__ __align__(16) unsigned short s_xw[7 * 64 * 16 * 8];   // 114688 B window
    __shared__ __align__(16) unsigned short s_val[2][64 * PITCH];    // 18432 B dbuf
    __shared__ float4 s_cw[18][64];                                  // 18432 B
    __shared__ int    s_pk[18][64];                                  // 4608 B

    unsigned short* s_om = &s_val[0][0];     // alias: s_om (7128 B) lives pre-P2

    const int t  = threadIdx.x;              // [0,1024)
    const int id = blockIdx.x;               // [0,512)
    const int b  = id & 7;                   // XCD-aware: batch b -> XCD b
    const int ho = id >> 3;                  // full output row

    const int lane = t & 63;
    const int wv   = t >> 6;                 // wave id 0..15
    const int lr   = lane & 15;              // MFMA row/col part
    const int lk   = (lane >> 4) * 8;        // MFMA k offset (shorts)
    const int q    = lane >> 4;              // D row quad

    const int lo = max(0, ho - 3);
    const int hi = min(Hn - 1, ho + 3);
    const int nrows = hi - lo + 1;           // <= 7

    const float* xb4 = x + (size_t)b * Cn * Hn * Wn;   // NCHW batch base
    const short8 zz = {0, 0, 0, 0, 0, 0, 0, 0};

    // ---- S: stage x window rows [lo,hi] into LDS, transposing on the fly ----
    for (int u = t; u < nrows * 1024; u += 1024) {
        int xx = u & 63;
        int kk = (u >> 6) & 15;
        int rs = u >> 10;
        int y  = lo + rs;
        short8 v;
#pragma unroll
        for (int j = 0; j < 8; ++j) {
            float f = xb4[(((size_t)(kk * 8 + j) * Hn) + y) * Wn + xx];
            v[j] = (short)f2bf(f);
        }
        *(short8*)&s_xw[(((rs * 64 + xx) * 16) + (kk ^ (xx & 15))) * 8] = v;
    }
    __syncthreads();

    // ---- P0: offset-conv GEMM on ALL 16 waves, A from LDS window ----
    {
        const int cg = wv >> 3;              // conv/deform group
        const int rh4 = (wv >> 1) & 3;       // row quarter (pos base rh4*16)
        const int nh = wv & 1;               // oc 16-block
        const int oc_l = nh * 16 + lr;
        float bias = (oc_l < 27) ? ob[cg * 27 + oc_l] : 0.f;
        f32x4 oacc = (f32x4){bias, bias, bias, bias};

        const unsigned short* wf = owf + (size_t)cg * 18432;

        for (int tap = 0; tap < 9; ++tap) {
            int ky = tap / 3, kx = tap - ky * 3;
            int y = ho - 2 + 2 * ky;
            if (y < 0 || y >= Hn) continue;  // wave-uniform skip (zero pad)
            int slot = y - lo;               // y in [lo,hi] guaranteed
#pragma unroll
            for (int ch = 0; ch < 2; ++ch) {
                int kssl = tap * 2 + ch;
                short8 bv = *(const short8*)&wf[(size_t)kssl * 1024 + nh * 512 + lane * 8];
                int wo = rh4 * 16 + lr;
                int xc = wo - 2 + 2 * kx;
                bool vx = (xc >= 0) & (xc < Wn);
                int xcc = min(max(xc, 0), Wn - 1);
                int kk  = (cg * 8 + ch * 4 + (lane >> 4)) ^ (xcc & 15);
                short8 av = *(const short8*)&s_xw[(((slot * 64 + xcc) * 16) + kk) * 8];
                av = vx ? av : zz;
                oacc = __builtin_amdgcn_mfma_f32_16x16x32_bf16(av, bv, oacc, 0, 0, 0);
            }
        }
        if (oc_l < 27) {
            int c54 = cg * 27 + oc_l;
#pragma unroll
            for (int r = 0; r < 4; ++r)
                s_om[c54 * OMP3 + rh4 * 16 + q * 4 + r] = f2bf(oacc[r]);
        }
    }
    __syncthreads();

    // ---- P1: sampling params for all (gk, pos) of this row ----
    for (int e = t; e < 18 * 64; e += 1024) {
        int pos = e & 63;
        int wo  = pos;
        int gk  = e >> 6;
        int g  = gk / 9, k = gk - g * 9;
        int ky = k / 3,  kx = k - ky * 3;
        float offy = bf2f(s_om[(g * 18 + k * 2 + 0) * OMP3 + pos]);
        float offx = bf2f(s_om[(g * 18 + k * 2 + 1) * OMP3 + pos]);
        float mk   = bf2f(s_om[(36 + g * 9 + k) * OMP3 + pos]);
        mk = 2.0f / (1.0f + __expf(-mk));

        float py = offy + (float)(ky * 2 + ho - 2);
        float px = offx + (float)(kx * 2 + wo - 2);
        float fy = floorf(py), fx = floorf(px);
        int   y0 = (int)fy,    x0 = (int)fx;
        float wy = py - fy,    wx = px - fx;

        bool vy0 = (y0 >= 0) & (y0 < Hn);
        bool vy1 = (y0 + 1 >= 0) & (y0 + 1 < Hn);
        bool vx0 = (x0 >= 0) & (x0 < Wn);
        bool vx1 = (x0 + 1 >= 0) & (x0 + 1 < Wn);
        float4 cw;
        cw.x = (vy0 & vx0) ? (1.f - wy) * (1.f - wx) * mk : 0.f;
        cw.y = (vy0 & vx1) ? (1.f - wy) * wx * mk : 0.f;
        cw.z = (vy1 & vx0) ? wy * (1.f - wx) * mk : 0.f;
        cw.w = (vy1 & vx1) ? wy * wx * mk : 0.f;

        int y0c = min(max(y0, 0), Hn - 1);
        int y1c = min(max(y0 + 1, 0), Hn - 1);
        int x0c = min(max(x0, 0), Wn - 1);
        int x1c = min(max(x0 + 1, 0), Wn - 1);
        s_cw[gk][pos] = cw;
        s_pk[gk][pos] = y0c | (y1c << 8) | (x0c << 16) | (x1c << 24);
    }
    __syncthreads();   // also fences s_om -> s_val reuse

    // ---- P2: producer/consumer loop with enforced pipelines ----
    const int pos = t >> 3;                  // producer: position 0..63
    const int c8  = t & 7;                   // producer: 8-ch chunk id

    // producer pipeline state
    float4 cwA;
    short8 a00A, a01A, a10A, a11A;

    auto load_state = [&](int gkj) {
        const int g = (gkj >= 9) ? 1 : 0;
        cwA = s_cw[gkj][pos];
        int pk  = s_pk[gkj][pos];
        int y0c = pk & 255, y1c = (pk >> 8) & 255;
        int x0c = (pk >> 16) & 255, x1c = (pk >> 24) & 255;
        bool ok = (y0c >= lo) & (y1c <= hi);
        if (__all(ok)) {
            const int kg = g * 8 + c8;
            a00A = *(const short8*)&s_xw[((((y0c - lo) * 64 + x0c) * 16) + (kg ^ (x0c & 15))) * 8];
            a01A = *(const short8*)&s_xw[((((y0c - lo) * 64 + x1c) * 16) + (kg ^ (x1c & 15))) * 8];
            a10A = *(const short8*)&s_xw[((((y1c - lo) * 64 + x0c) * 16) + (kg ^ (x0c & 15))) * 8];
            a11A = *(const short8*)&s_xw[((((y1c - lo) * 64 + x1c) * 16) + (kg ^ (x1c & 15))) * 8];
        } else {
            const float* xc0 = xb4 + (size_t)(g * Cgn + c8 * 8) * Hn * Wn;
#pragma unroll
            for (int j = 0; j < 8; ++j) {
                const float* xj = xc0 + (size_t)j * Hn * Wn;
                a00A[j] = (short)f2bf(xj[(size_t)y0c * Wn + x0c]);
                a01A[j] = (short)f2bf(xj[(size_t)y0c * Wn + x1c]);
                a10A[j] = (short)f2bf(xj[(size_t)y1c * Wn + x0c]);
                a11A[j] = (short)f2bf(xj[(size_t)y1c * Wn + x1c]);
            }
        }
    };

    auto emit_tile = [&](int buf) {
        short8 h0;
#pragma unroll
        for (int i = 0; i < 8; ++i) {
            float v = cwA.x * bf2f((unsigned short)a00A[i]) +
                      cwA.y * bf2f((unsigned short)a01A[i]) +
                      cwA.z * bf2f((unsigned short)a10A[i]) +
                      cwA.w * bf2f((unsigned short)a11A[i]);
            h0[i] = (short)f2bf(v);
        }
        *(short8*)&s_val[buf][pos * PITCH + c8 * 8] = h0;
    };

    f32x4 acc[2][2];
#pragma unroll
    for (int i = 0; i < 2; ++i)
#pragma unroll
        for (int j = 0; j < 2; ++j) acc[i][j] = (f32x4){0.f, 0.f, 0.f, 0.f};

    const int cid = wv - 8;                  // consumer id 0..7 (wv >= 8)
    const int rh2 = cid >> 2;                // mt pair: rows (rh2*2+i)*16
    const int nt2 = cid & 3;                 // oc-32: tiles nt2*2 + j

    short8 bfrA[4];                          // consumer resident B-frags

    if (wv < 8) {
        load_state(0);
        emit_tile(0);                        // prologue: buf0 = gk 0
        load_state(1);                       // prefetch gk 1
    } else {
        // prologue: B-frags for gk 0
#pragma unroll
        for (int ks = 0; ks < 2; ++ks)
#pragma unroll
            for (int j = 0; j < 2; ++j)
                bfrA[ks * 2 + j] = *(const short8*)&wt2[(size_t)(ks * 8 + nt2 * 2 + j) * 512 + lane * 8];
    }

    for (int gk = 0; gk < 18; ++gk) {
        BARRIER_NODRAIN();                   // s_val[gk&1] ready; vmem rides
        if (wv < 8) {
            if (gk < 17) {
                emit_tile((gk + 1) & 1);     // state resident: no LDS latency
                if (gk < 16) load_state(gk + 2);
            }
        } else {
            // issue NEXT gk's B-frag loads first; pin with sched_barrier
            short8 bfrN[4];
            if (gk < 17) {
                const unsigned short* wfn = wt2 + (size_t)(gk + 1) * 8192;
#pragma unroll
                for (int ks = 0; ks < 2; ++ks)
#pragma unroll
                    for (int j = 0; j < 2; ++j)
                        bfrN[ks * 2 + j] = *(const short8*)&wfn[(size_t)(ks * 8 + nt2 * 2 + j) * 512 + lane * 8];
            }
            __builtin_amdgcn_sched_barrier(0);   // loads may not sink below

            const int bufc = gk & 1;
#pragma unroll
            for (int ks = 0; ks < 2; ++ks) {
                short8 af[2];
#pragma unroll
                for (int i = 0; i < 2; ++i)
                    af[i] = *(const short8*)&s_val[bufc][((rh2 * 2 + i) * 16 + lr) * PITCH + ks * 32 + lk];
#pragma unroll
                for (int i = 0; i < 2; ++i)
#pragma unroll
                    for (int j = 0; j < 2; ++j)
                        acc[i][j] = __builtin_amdgcn_mfma_f32_16x16x32_bf16(
                            af[i], bfrA[ks * 2 + j], acc[i][j], 0, 0, 0);
            }
            if (gk < 17) {
#pragma unroll
                for (int r = 0; r < 4; ++r) bfrA[r] = bfrN[r];
            }
        }
    }

    // ---- epilogue (consumers): oc = (nt2*2+j)*16 + lr; rows (rh2*2+i)*16 + q*4 ----
    if (wv >= 8) {
#pragma unroll
        for (int i = 0; i < 2; ++i)
#pragma unroll
            for (int j = 0; j < 2; ++j) {
                int oc = (nt2 * 2 + j) * 16 + lr;
                int p0 = (rh2 * 2 + i) * 16 + q * 4;
                float4 v = {acc[i][j][0], acc[i][j][1], acc[i][j][2], acc[i][j][3]};
                *(float4*)&out[(((size_t)b * Con + oc) * HOn + ho) * WOn + p0] = v;
            }
    }
}

// ---------------------------------------------------------------------------
extern "C" void kernel_launch(void* const* d_in, const int* in_sizes, int n_in,
                              void* d_out, int out_size, void* d_ws, size_t ws_size,
                              hipStream_t stream) {
    const float* x  = (const float*)d_in[0];   // [8,128,64,64]
    const float* ow = (const float*)d_in[1];   // [54,64,3,3]
    const float* ob = (const float*)d_in[2];   // [54]
    const float* w  = (const float*)d_in[3];   // [128,128,3,3]
    float* out = (float*)d_out;                // [8,128,64,64]

    // ws: wt2 294,912 | owf 73,728
    unsigned short* wt2 = (unsigned short*)d_ws;
    unsigned short* owf = (unsigned short*)((char*)d_ws + 294912);

    hipLaunchKernelGGL(prep, dim3(720), dim3(256), 0, stream,
                       w, ow, wt2, owf);
    hipLaunchKernelGGL(dcn_fused, dim3(512), dim3(1024), 0, stream,
                       x, owf, ob, wt2, out);
}

// Round 14
// 113.249 us; speedup vs baseline: 1.0056x; 1.0028x over previous
//
#include <hip/hip_runtime.h>
#include <hip/hip_bf16.h>

// Problem constants
static constexpr int Bn = 8, Cn = 128, Hn = 64, Wn = 64, Con = 128;
static constexpr int KKn = 9, DGn = 2, Cgn = 64;
static constexpr int HOn = 64, WOn = 64;
static constexpr int PITCH = 72;     // bf16 row pitch for s_val rows
static constexpr int OMP3 = 66;      // s_om row pitch (shorts), 64 pos + pad

typedef short short8 __attribute__((ext_vector_type(8)));
typedef float f32x4  __attribute__((ext_vector_type(4)));

__device__ __forceinline__ unsigned short f2bf(float f) {
    unsigned u = __float_as_uint(f);
    u += 0x7fff + ((u >> 16) & 1);          // round-to-nearest-even
    return (unsigned short)(u >> 16);
}
__device__ __forceinline__ float bf2f(unsigned short h) {
    return __uint_as_float(((unsigned)h) << 16);
}

// ---------------------------------------------------------------------------
// Kernel P (R18, proven): WEIGHTS-ONLY prep.
// Blocks [0,576):   main weight -> MFMA B-frag order wt2[gk][ks][tile][lane][8].
// Blocks [576,720): offset weight -> owf[g][ks=tap*2+ch][nt][lane][8].
// ---------------------------------------------------------------------------
__global__ __launch_bounds__(256) void prep(const float* __restrict__ w,
                                            const float* __restrict__ ow,
                                            unsigned short* __restrict__ wt2,
                                            unsigned short* __restrict__ owf) {
    const int blk = blockIdx.x;
    const int t = threadIdx.x;
    if (blk < 576) {
        int e    = blk * 256 + t;                // [0,147456)
        int j    = e & 7;
        int lane = (e >> 3) & 63;
        int tile = (e >> 9) & 7;
        int ks   = (e >> 12) & 1;
        int gk   = e >> 13;                      // 0..17
        int g = gk / 9, k = gk - g * 9;
        int oc = tile * 16 + (lane & 15);
        int c  = ks * 32 + (lane >> 4) * 8 + j;
        wt2[e] = f2bf(w[((size_t)oc * Cn + g * Cgn + c) * KKn + k]);
    } else {
        int e = (blk - 576) * 256 + t;           // [0,36864)
        int g  = e / 18432;
        int r  = e - g * 18432;
        int ks = r >> 10;
        int r2 = r & 1023;
        int nt = r2 >> 9;
        int lane = (r2 >> 3) & 63;
        int j  = r2 & 7;
        int tap = ks >> 1, chalf = ks & 1;
        int oc_l = nt * 16 + (lane & 15);
        int c = chalf * 32 + (lane >> 4) * 8 + j;
        float v = 0.f;
        if (oc_l < 27)
            v = ow[((size_t)(g * 27 + oc_l) * Cgn + c) * KKn + tap];
        owf[e] = f2bf(v);
    }
}

// ---------------------------------------------------------------------------
// Kernel 2 (R22): R18 VERBATIM (best measured: dcn 47.4us, total 112.2)
// + T5 producer wave priority.
// Post-mortems R9/R10/R16/R17/R19/R20/R21: six schedule/latency attempts all
// null or negative -> producer waves are the per-round pole (VALUBusy ~45%,
// everything else <30%). setprio(1) on producer waves biases the CU issue
// arbiter toward the critical path; consumers have barrier slack. Pure hint:
// no structural or numeric change; output bit-identical.
// LDS: 114688 (s_xw) + 18432 (s_val dbuf, s_om aliased) + 18432 (s_cw)
//      + 4608 (s_pk) = 156160 B -> 1 block/CU, 16 waves.
// ---------------------------------------------------------------------------
__global__ __launch_bounds__(1024, 4) void dcn_fused(const float* __restrict__ x,
                                                     const unsigned short* __restrict__ owf,
                                                     const float* __restrict__ ob,
                                                     const unsigned short* __restrict__ wt2,
                                                     float* __restrict__ out) {
    __shared__ __align__(16) unsigned short s_xw[7 * 64 * 16 * 8];   // 114688 B window
    __shared__ __align__(16) unsigned short s_val[2][64 * PITCH];    // 18432 B dbuf
    __shared__ float4 s_cw[18][64];                                  // 18432 B
    __shared__ int    s_pk[18][64];                                  // 4608 B

    unsigned short* s_om = &s_val[0][0];     // alias: s_om (7128 B) lives pre-P2

    const int t  = threadIdx.x;              // [0,1024)
    const int id = blockIdx.x;               // [0,512)
    const int b  = id & 7;                   // XCD-aware: batch b -> XCD b
    const int ho = id >> 3;                  // full output row

    const int lane = t & 63;
    const int wv   = t >> 6;                 // wave id 0..15
    const int lr   = lane & 15;              // MFMA row/col part
    const int lk   = (lane >> 4) * 8;        // MFMA k offset (shorts)
    const int q    = lane >> 4;              // D row quad

    const int lo = max(0, ho - 3);
    const int hi = min(Hn - 1, ho + 3);
    const int nrows = hi - lo + 1;           // <= 7

    const float* xb4 = x + (size_t)b * Cn * Hn * Wn;   // NCHW batch base
    const short8 zz = {0, 0, 0, 0, 0, 0, 0, 0};

    // ---- S: stage x window rows [lo,hi] into LDS, transposing on the fly ----
    for (int u = t; u < nrows * 1024; u += 1024) {
        int xx = u & 63;
        int kk = (u >> 6) & 15;
        int rs = u >> 10;
        int y  = lo + rs;
        short8 v;
#pragma unroll
        for (int j = 0; j < 8; ++j) {
            float f = xb4[(((size_t)(kk * 8 + j) * Hn) + y) * Wn + xx];
            v[j] = (short)f2bf(f);
        }
        *(short8*)&s_xw[(((rs * 64 + xx) * 16) + (kk ^ (xx & 15))) * 8] = v;
    }
    __syncthreads();

    // ---- P0: offset-conv GEMM on ALL 16 waves, A from LDS window ----
    {
        const int cg = wv >> 3;              // conv/deform group
        const int rh4 = (wv >> 1) & 3;       // row quarter (pos base rh4*16)
        const int nh = wv & 1;               // oc 16-block
        const int oc_l = nh * 16 + lr;
        float bias = (oc_l < 27) ? ob[cg * 27 + oc_l] : 0.f;
        f32x4 oacc = (f32x4){bias, bias, bias, bias};

        const unsigned short* wf = owf + (size_t)cg * 18432;

        for (int tap = 0; tap < 9; ++tap) {
            int ky = tap / 3, kx = tap - ky * 3;
            int y = ho - 2 + 2 * ky;
            if (y < 0 || y >= Hn) continue;  // wave-uniform skip (zero pad)
            int slot = y - lo;               // y in [lo,hi] guaranteed
#pragma unroll
            for (int ch = 0; ch < 2; ++ch) {
                int kssl = tap * 2 + ch;
                short8 bv = *(const short8*)&wf[(size_t)kssl * 1024 + nh * 512 + lane * 8];
                int wo = rh4 * 16 + lr;
                int xc = wo - 2 + 2 * kx;
                bool vx = (xc >= 0) & (xc < Wn);
                int xcc = min(max(xc, 0), Wn - 1);
                int kk  = (cg * 8 + ch * 4 + (lane >> 4)) ^ (xcc & 15);
                short8 av = *(const short8*)&s_xw[(((slot * 64 + xcc) * 16) + kk) * 8];
                av = vx ? av : zz;
                oacc = __builtin_amdgcn_mfma_f32_16x16x32_bf16(av, bv, oacc, 0, 0, 0);
            }
        }
        if (oc_l < 27) {
            int c54 = cg * 27 + oc_l;
#pragma unroll
            for (int r = 0; r < 4; ++r)
                s_om[c54 * OMP3 + rh4 * 16 + q * 4 + r] = f2bf(oacc[r]);
        }
    }
    __syncthreads();

    // ---- P1: sampling params for all (gk, pos) of this row ----
    for (int e = t; e < 18 * 64; e += 1024) {
        int pos = e & 63;
        int wo  = pos;
        int gk  = e >> 6;
        int g  = gk / 9, k = gk - g * 9;
        int ky = k / 3,  kx = k - ky * 3;
        float offy = bf2f(s_om[(g * 18 + k * 2 + 0) * OMP3 + pos]);
        float offx = bf2f(s_om[(g * 18 + k * 2 + 1) * OMP3 + pos]);
        float mk   = bf2f(s_om[(36 + g * 9 + k) * OMP3 + pos]);
        mk = 2.0f / (1.0f + __expf(-mk));

        float py = offy + (float)(ky * 2 + ho - 2);
        float px = offx + (float)(kx * 2 + wo - 2);
        float fy = floorf(py), fx = floorf(px);
        int   y0 = (int)fy,    x0 = (int)fx;
        float wy = py - fy,    wx = px - fx;

        bool vy0 = (y0 >= 0) & (y0 < Hn);
        bool vy1 = (y0 + 1 >= 0) & (y0 + 1 < Hn);
        bool vx0 = (x0 >= 0) & (x0 < Wn);
        bool vx1 = (x0 + 1 >= 0) & (x0 + 1 < Wn);
        float4 cw;
        cw.x = (vy0 & vx0) ? (1.f - wy) * (1.f - wx) * mk : 0.f;
        cw.y = (vy0 & vx1) ? (1.f - wy) * wx * mk : 0.f;
        cw.z = (vy1 & vx0) ? wy * (1.f - wx) * mk : 0.f;
        cw.w = (vy1 & vx1) ? wy * wx * mk : 0.f;

        int y0c = min(max(y0, 0), Hn - 1);
        int y1c = min(max(y0 + 1, 0), Hn - 1);
        int x0c = min(max(x0, 0), Wn - 1);
        int x1c = min(max(x0 + 1, 0), Wn - 1);
        s_cw[gk][pos] = cw;
        s_pk[gk][pos] = y0c | (y1c << 8) | (x0c << 16) | (x1c << 24);
    }
    __syncthreads();   // also fences s_om -> s_val reuse

    // ---- P2: producer/consumer gk loop (R18 verbatim) + producer priority ----
    if (wv < 8) __builtin_amdgcn_s_setprio(1);   // T5: bias issue arbiter
                                                 // toward the pole waves

    auto gather_tile = [&](int gkj) {
        const int pos = t >> 3;              // 0..63 (t < 512)
        const int c8  = t & 7;               // 8-ch chunk id
        const int g   = (gkj >= 9) ? 1 : 0;
        float4 cw = s_cw[gkj][pos];
        int pk  = s_pk[gkj][pos];
        int y0c = pk & 255, y1c = (pk >> 8) & 255;
        int x0c = (pk >> 16) & 255, x1c = (pk >> 24) & 255;

        short8 a00, a01, a10, a11;
        bool ok = (y0c >= lo) & (y1c <= hi);
        if (__all(ok)) {
            const int kg = g * 8 + c8;
            a00 = *(const short8*)&s_xw[((((y0c - lo) * 64 + x0c) * 16) + (kg ^ (x0c & 15))) * 8];
            a01 = *(const short8*)&s_xw[((((y0c - lo) * 64 + x1c) * 16) + (kg ^ (x1c & 15))) * 8];
            a10 = *(const short8*)&s_xw[((((y1c - lo) * 64 + x0c) * 16) + (kg ^ (x0c & 15))) * 8];
            a11 = *(const short8*)&s_xw[((((y1c - lo) * 64 + x1c) * 16) + (kg ^ (x1c & 15))) * 8];
        } else {
            // rare fallback (offsets beyond window): read NCHW x directly.
            const float* xc0 = xb4 + (size_t)(g * Cgn + c8 * 8) * Hn * Wn;
#pragma unroll
            for (int j = 0; j < 8; ++j) {
                const float* xj = xc0 + (size_t)j * Hn * Wn;
                a00[j] = (short)f2bf(xj[(size_t)y0c * Wn + x0c]);
                a01[j] = (short)f2bf(xj[(size_t)y0c * Wn + x1c]);
                a10[j] = (short)f2bf(xj[(size_t)y1c * Wn + x0c]);
                a11[j] = (short)f2bf(xj[(size_t)y1c * Wn + x1c]);
            }
        }
        short8 h0;
#pragma unroll
        for (int i = 0; i < 8; ++i) {
            float v = cw.x * bf2f((unsigned short)a00[i]) +
                      cw.y * bf2f((unsigned short)a01[i]) +
                      cw.z * bf2f((unsigned short)a10[i]) +
                      cw.w * bf2f((unsigned short)a11[i]);
            h0[i] = (short)f2bf(v);
        }
        *(short8*)&s_val[gkj & 1][(t >> 3) * PITCH + c8 * 8] = h0;
    };

    f32x4 acc[2][2];                         // [i = mt in pair][j = oc-16 in pair]
#pragma unroll
    for (int i = 0; i < 2; ++i)
#pragma unroll
        for (int j = 0; j < 2; ++j) acc[i][j] = (f32x4){0.f, 0.f, 0.f, 0.f};

    if (wv < 8) gather_tile(0);              // prologue fill buf0

    const int cid = wv - 8;                  // consumer id 0..7 (wv >= 8)
    const int rh2 = cid >> 2;                // mt pair: rows (rh2*2+i)*16
    const int nt2 = cid & 3;                 // oc-32: tiles nt2*2 + j

    for (int gk = 0; gk < 18; ++gk) {
        __syncthreads();                     // s_val[gk&1] ready for consumers
        if (wv < 8) {
            if (gk < 17) gather_tile(gk + 1);   // fill other buffer concurrently
        } else {
            const unsigned short* wf = wt2 + (size_t)gk * 8192;
#pragma unroll
            for (int ks = 0; ks < 2; ++ks) {
                short8 af[2];
#pragma unroll
                for (int i = 0; i < 2; ++i)
                    af[i] = *(const short8*)&s_val[gk & 1][((rh2 * 2 + i) * 16 + lr) * PITCH + ks * 32 + lk];
#pragma unroll
                for (int i = 0; i < 2; ++i)
#pragma unroll
                    for (int j = 0; j < 2; ++j) {
                        short8 bfr = *(const short8*)&wf[(size_t)(ks * 8 + nt2 * 2 + j) * 512 + lane * 8];
                        acc[i][j] = __builtin_amdgcn_mfma_f32_16x16x32_bf16(af[i], bfr, acc[i][j], 0, 0, 0);
                    }
            }
        }
    }

    if (wv < 8) __builtin_amdgcn_s_setprio(0);

    // ---- epilogue (consumers): oc = (nt2*2+j)*16 + lr; rows (rh2*2+i)*16 + q*4 ----
    if (wv >= 8) {
#pragma unroll
        for (int i = 0; i < 2; ++i)
#pragma unroll
            for (int j = 0; j < 2; ++j) {
                int oc = (nt2 * 2 + j) * 16 + lr;
                int p0 = (rh2 * 2 + i) * 16 + q * 4;
                float4 v = {acc[i][j][0], acc[i][j][1], acc[i][j][2], acc[i][j][3]};
                *(float4*)&out[(((size_t)b * Con + oc) * HOn + ho) * WOn + p0] = v;
            }
    }
}

// ---------------------------------------------------------------------------
extern "C" void kernel_launch(void* const* d_in, const int* in_sizes, int n_in,
                              void* d_out, int out_size, void* d_ws, size_t ws_size,
                              hipStream_t stream) {
    const float* x  = (const float*)d_in[0];   // [8,128,64,64]
    const float* ow = (const float*)d_in[1];   // [54,64,3,3]
    const float* ob = (const float*)d_in[2];   // [54]
    const float* w  = (const float*)d_in[3];   // [128,128,3,3]
    float* out = (float*)d_out;                // [8,128,64,64]

    // ws: wt2 294,912 | owf 73,728
    unsigned short* wt2 = (unsigned short*)d_ws;
    unsigned short* owf = (unsigned short*)((char*)d_ws + 294912);

    hipLaunchKernelGGL(prep, dim3(720), dim3(256), 0, stream,
                       w, ow, wt2, owf);
    hipLaunchKernelGGL(dcn_fused, dim3(512), dim3(1024), 0, stream,
                       x, owf, ob, wt2, out);
}

// Round 15
// 112.816 us; speedup vs baseline: 1.0095x; 1.0038x over previous
//
#include <hip/hip_runtime.h>
#include <hip/hip_bf16.h>

// Problem constants
static constexpr int Bn = 8, Cn = 128, Hn = 64, Wn = 64, Con = 128;
static constexpr int KKn = 9, DGn = 2, Cgn = 64;
static constexpr int HOn = 64, WOn = 64;
static constexpr int PITCH = 72;     // bf16 row pitch for s_val rows
static constexpr int OMP3 = 66;      // s_om row pitch (shorts), 64 pos + pad

typedef short short8 __attribute__((ext_vector_type(8)));
typedef float f32x4  __attribute__((ext_vector_type(4)));

__device__ __forceinline__ unsigned short f2bf(float f) {
    unsigned u = __float_as_uint(f);
    u += 0x7fff + ((u >> 16) & 1);          // round-to-nearest-even
    return (unsigned short)(u >> 16);
}
__device__ __forceinline__ float bf2f(unsigned short h) {
    return __uint_as_float(((unsigned)h) << 16);
}

// ---------------------------------------------------------------------------
// Kernel P (R18, proven): WEIGHTS-ONLY prep.
// Blocks [0,576):   main weight -> MFMA B-frag order wt2[gk][ks][tile][lane][8].
// Blocks [576,720): offset weight -> owf[g][ks=tap*2+ch][nt][lane][8].
// ---------------------------------------------------------------------------
__global__ __launch_bounds__(256) void prep(const float* __restrict__ w,
                                            const float* __restrict__ ow,
                                            unsigned short* __restrict__ wt2,
                                            unsigned short* __restrict__ owf) {
    const int blk = blockIdx.x;
    const int t = threadIdx.x;
    if (blk < 576) {
        int e    = blk * 256 + t;                // [0,147456)
        int j    = e & 7;
        int lane = (e >> 3) & 63;
        int tile = (e >> 9) & 7;
        int ks   = (e >> 12) & 1;
        int gk   = e >> 13;                      // 0..17
        int g = gk / 9, k = gk - g * 9;
        int oc = tile * 16 + (lane & 15);
        int c  = ks * 32 + (lane >> 4) * 8 + j;
        wt2[e] = f2bf(w[((size_t)oc * Cn + g * Cgn + c) * KKn + k]);
    } else {
        int e = (blk - 576) * 256 + t;           // [0,36864)
        int g  = e / 18432;
        int r  = e - g * 18432;
        int ks = r >> 10;
        int r2 = r & 1023;
        int nt = r2 >> 9;
        int lane = (r2 >> 3) & 63;
        int j  = r2 & 7;
        int tap = ks >> 1, chalf = ks & 1;
        int oc_l = nt * 16 + (lane & 15);
        int c = chalf * 32 + (lane >> 4) * 8 + j;
        float v = 0.f;
        if (oc_l < 27)
            v = ow[((size_t)(g * 27 + oc_l) * Cgn + c) * KKn + tap];
        owf[e] = f2bf(v);
    }
}

// ---------------------------------------------------------------------------
// Kernel 2 (R23): gk-PAIR rounds + 4-buffer s_val, cw spilled to global.
// Accounting after 8 nulls: P2 time ~ LDS-unit occupancy (~1000cy/round:
// producer cw+pk+corners+write, consumer af) + 18 barrier quanta +
// producer dependency bubbles (2 waves/SIMD can't hide LDS latency).
// R23 attacks all three at once, math unchanged (bit-identical):
//   - s_cw -> g_cw in workspace (L2-resident, written by P1, read by
//     producers as hidable global loads). Frees 18,432 B LDS and 144
//     b128 LDS reads/block.
//   - s_val becomes 4 buffers (tile T -> buf T&3); P2 runs 9 pair-rounds:
//     consumers MFMA tiles {2p, 2p+1} (gk asc, ks asc preserved),
//     producers gather tiles {2p+2, 2p+3} = TWO independent chains per
//     thread (ILP x2 on the bubble path). Reads {2p,2p+1}&3 vs writes
//     {2p+2,2p+3}&3 disjoint -> race-free with one barrier per round.
//     Barriers 18 -> 9.
// Stage/P0/P1-math/gather-math/consumer-inner/epilogue: R18 verbatim.
// LDS: 114688 (s_xw) + 36864 (s_val x4, s_om aliased) + 4608 (s_pk)
//      = 156160 B -> 1 block/CU, 16 waves.
// ---------------------------------------------------------------------------
__global__ __launch_bounds__(1024, 4) void dcn_fused(const float* __restrict__ x,
                                                     const unsigned short* __restrict__ owf,
                                                     const float* __restrict__ ob,
                                                     const unsigned short* __restrict__ wt2,
                                                     float4* __restrict__ g_cw,
                                                     float* __restrict__ out) {
    __shared__ __align__(16) unsigned short s_xw[7 * 64 * 16 * 8];   // 114688 B window
    __shared__ __align__(16) unsigned short s_val[4][64 * PITCH];    // 36864 B, 4 bufs
    __shared__ int    s_pk[18][64];                                  // 4608 B

    unsigned short* s_om = &s_val[0][0];     // alias: s_om (7128 B) lives pre-P2

    const int t  = threadIdx.x;              // [0,1024)
    const int id = blockIdx.x;               // [0,512)
    const int b  = id & 7;                   // XCD-aware: batch b -> XCD b
    const int ho = id >> 3;                  // full output row

    const int lane = t & 63;
    const int wv   = t >> 6;                 // wave id 0..15
    const int lr   = lane & 15;              // MFMA row/col part
    const int lk   = (lane >> 4) * 8;        // MFMA k offset (shorts)
    const int q    = lane >> 4;              // D row quad

    const int lo = max(0, ho - 3);
    const int hi = min(Hn - 1, ho + 3);
    const int nrows = hi - lo + 1;           // <= 7

    const float* xb4 = x + (size_t)b * Cn * Hn * Wn;   // NCHW batch base
    float4* g_cwb = g_cw + (size_t)(b * 64 + ho) * 1152;   // per-block scratch
    const short8 zz = {0, 0, 0, 0, 0, 0, 0, 0};

    // ---- S: stage x window rows [lo,hi] into LDS, transposing on the fly ----
    for (int u = t; u < nrows * 1024; u += 1024) {
        int xx = u & 63;
        int kk = (u >> 6) & 15;
        int rs = u >> 10;
        int y  = lo + rs;
        short8 v;
#pragma unroll
        for (int j = 0; j < 8; ++j) {
            float f = xb4[(((size_t)(kk * 8 + j) * Hn) + y) * Wn + xx];
            v[j] = (short)f2bf(f);
        }
        *(short8*)&s_xw[(((rs * 64 + xx) * 16) + (kk ^ (xx & 15))) * 8] = v;
    }
    __syncthreads();

    // ---- P0: offset-conv GEMM on ALL 16 waves, A from LDS window ----
    {
        const int cg = wv >> 3;              // conv/deform group
        const int rh4 = (wv >> 1) & 3;       // row quarter (pos base rh4*16)
        const int nh = wv & 1;               // oc 16-block
        const int oc_l = nh * 16 + lr;
        float bias = (oc_l < 27) ? ob[cg * 27 + oc_l] : 0.f;
        f32x4 oacc = (f32x4){bias, bias, bias, bias};

        const unsigned short* wf = owf + (size_t)cg * 18432;

        for (int tap = 0; tap < 9; ++tap) {
            int ky = tap / 3, kx = tap - ky * 3;
            int y = ho - 2 + 2 * ky;
            if (y < 0 || y >= Hn) continue;  // wave-uniform skip (zero pad)
            int slot = y - lo;               // y in [lo,hi] guaranteed
#pragma unroll
            for (int ch = 0; ch < 2; ++ch) {
                int kssl = tap * 2 + ch;
                short8 bv = *(const short8*)&wf[(size_t)kssl * 1024 + nh * 512 + lane * 8];
                int wo = rh4 * 16 + lr;
                int xc = wo - 2 + 2 * kx;
                bool vx = (xc >= 0) & (xc < Wn);
                int xcc = min(max(xc, 0), Wn - 1);
                int kk  = (cg * 8 + ch * 4 + (lane >> 4)) ^ (xcc & 15);
                short8 av = *(const short8*)&s_xw[(((slot * 64 + xcc) * 16) + kk) * 8];
                av = vx ? av : zz;
                oacc = __builtin_amdgcn_mfma_f32_16x16x32_bf16(av, bv, oacc, 0, 0, 0);
            }
        }
        if (oc_l < 27) {
            int c54 = cg * 27 + oc_l;
#pragma unroll
            for (int r = 0; r < 4; ++r)
                s_om[c54 * OMP3 + rh4 * 16 + q * 4 + r] = f2bf(oacc[r]);
        }
    }
    __syncthreads();

    // ---- P1: sampling params; cw -> g_cw (global), pk -> LDS ----
    for (int e = t; e < 18 * 64; e += 1024) {
        int pos = e & 63;
        int wo  = pos;
        int gk  = e >> 6;
        int g  = gk / 9, k = gk - g * 9;
        int ky = k / 3,  kx = k - ky * 3;
        float offy = bf2f(s_om[(g * 18 + k * 2 + 0) * OMP3 + pos]);
        float offx = bf2f(s_om[(g * 18 + k * 2 + 1) * OMP3 + pos]);
        float mk   = bf2f(s_om[(36 + g * 9 + k) * OMP3 + pos]);
        mk = 2.0f / (1.0f + __expf(-mk));

        float py = offy + (float)(ky * 2 + ho - 2);
        float px = offx + (float)(kx * 2 + wo - 2);
        float fy = floorf(py), fx = floorf(px);
        int   y0 = (int)fy,    x0 = (int)fx;
        float wy = py - fy,    wx = px - fx;

        bool vy0 = (y0 >= 0) & (y0 < Hn);
        bool vy1 = (y0 + 1 >= 0) & (y0 + 1 < Hn);
        bool vx0 = (x0 >= 0) & (x0 < Wn);
        bool vx1 = (x0 + 1 >= 0) & (x0 + 1 < Wn);
        float4 cw;
        cw.x = (vy0 & vx0) ? (1.f - wy) * (1.f - wx) * mk : 0.f;
        cw.y = (vy0 & vx1) ? (1.f - wy) * wx * mk : 0.f;
        cw.z = (vy1 & vx0) ? wy * (1.f - wx) * mk : 0.f;
        cw.w = (vy1 & vx1) ? wy * wx * mk : 0.f;

        int y0c = min(max(y0, 0), Hn - 1);
        int y1c = min(max(y0 + 1, 0), Hn - 1);
        int x0c = min(max(x0, 0), Wn - 1);
        int x1c = min(max(x0 + 1, 0), Wn - 1);
        g_cwb[e] = cw;                        // per-block scratch, L2-resident
        s_pk[gk][pos] = y0c | (y1c << 8) | (x0c << 16) | (x1c << 24);
    }
    __syncthreads();   // fences s_om -> s_val reuse; drains g_cw stores (vmcnt)

    // ---- P2: pair-rounds; producers fill {2p+2,2p+3}, consumers MFMA {2p,2p+1} ----
    const int pos = t >> 3;                  // producer: position 0..63
    const int c8  = t & 7;                   // producer: 8-ch chunk id

    auto gather_tile = [&](int T) {
        const int g = (T >= 9) ? 1 : 0;
        float4 cw = g_cwb[T * 64 + pos];     // global read (L2, hidable)
        int pk  = s_pk[T][pos];
        int y0c = pk & 255, y1c = (pk >> 8) & 255;
        int x0c = (pk >> 16) & 255, x1c = (pk >> 24) & 255;

        short8 a00, a01, a10, a11;
        bool ok = (y0c >= lo) & (y1c <= hi);
        if (__all(ok)) {
            const int kg = g * 8 + c8;
            a00 = *(const short8*)&s_xw[((((y0c - lo) * 64 + x0c) * 16) + (kg ^ (x0c & 15))) * 8];
            a01 = *(const short8*)&s_xw[((((y0c - lo) * 64 + x1c) * 16) + (kg ^ (x1c & 15))) * 8];
            a10 = *(const short8*)&s_xw[((((y1c - lo) * 64 + x0c) * 16) + (kg ^ (x0c & 15))) * 8];
            a11 = *(const short8*)&s_xw[((((y1c - lo) * 64 + x1c) * 16) + (kg ^ (x1c & 15))) * 8];
        } else {
            // rare fallback (offsets beyond window): read NCHW x directly.
            const float* xc0 = xb4 + (size_t)(g * Cgn + c8 * 8) * Hn * Wn;
#pragma unroll
            for (int j = 0; j < 8; ++j) {
                const float* xj = xc0 + (size_t)j * Hn * Wn;
                a00[j] = (short)f2bf(xj[(size_t)y0c * Wn + x0c]);
                a01[j] = (short)f2bf(xj[(size_t)y0c * Wn + x1c]);
                a10[j] = (short)f2bf(xj[(size_t)y1c * Wn + x0c]);
                a11[j] = (short)f2bf(xj[(size_t)y1c * Wn + x1c]);
            }
        }
        short8 h0;
#pragma unroll
        for (int i = 0; i < 8; ++i) {
            float v = cw.x * bf2f((unsigned short)a00[i]) +
                      cw.y * bf2f((unsigned short)a01[i]) +
                      cw.z * bf2f((unsigned short)a10[i]) +
                      cw.w * bf2f((unsigned short)a11[i]);
            h0[i] = (short)f2bf(v);
        }
        *(short8*)&s_val[T & 3][pos * PITCH + c8 * 8] = h0;
    };

    f32x4 acc[2][2];                         // [i = mt in pair][j = oc-16 in pair]
#pragma unroll
    for (int i = 0; i < 2; ++i)
#pragma unroll
        for (int j = 0; j < 2; ++j) acc[i][j] = (f32x4){0.f, 0.f, 0.f, 0.f};

    if (wv < 8) {                            // prologue: tiles 0 and 1
        gather_tile(0);
        gather_tile(1);
    }

    const int cid = wv - 8;                  // consumer id 0..7 (wv >= 8)
    const int rh2 = cid >> 2;                // mt pair: rows (rh2*2+i)*16
    const int nt2 = cid & 3;                 // oc-32: tiles nt2*2 + j

    for (int p = 0; p < 9; ++p) {
        __syncthreads();                     // tiles 2p, 2p+1 ready
        if (wv < 8) {
            if (p < 8) {                     // two INDEPENDENT gathers (ILP x2)
                gather_tile(2 * p + 2);
                gather_tile(2 * p + 3);
            }
        } else {
#pragma unroll
            for (int tl = 0; tl < 2; ++tl) {
                const int T = 2 * p + tl;
                const unsigned short* wf = wt2 + (size_t)T * 8192;
#pragma unroll
                for (int ks = 0; ks < 2; ++ks) {
                    short8 af[2];
#pragma unroll
                    for (int i = 0; i < 2; ++i)
                        af[i] = *(const short8*)&s_val[T & 3][((rh2 * 2 + i) * 16 + lr) * PITCH + ks * 32 + lk];
#pragma unroll
                    for (int i = 0; i < 2; ++i)
#pragma unroll
                        for (int j = 0; j < 2; ++j) {
                            short8 bfr = *(const short8*)&wf[(size_t)(ks * 8 + nt2 * 2 + j) * 512 + lane * 8];
                            acc[i][j] = __builtin_amdgcn_mfma_f32_16x16x32_bf16(af[i], bfr, acc[i][j], 0, 0, 0);
                        }
                }
            }
        }
    }

    // ---- epilogue (consumers): oc = (nt2*2+j)*16 + lr; rows (rh2*2+i)*16 + q*4 ----
    if (wv >= 8) {
#pragma unroll
        for (int i = 0; i < 2; ++i)
#pragma unroll
            for (int j = 0; j < 2; ++j) {
                int oc = (nt2 * 2 + j) * 16 + lr;
                int p0 = (rh2 * 2 + i) * 16 + q * 4;
                float4 v = {acc[i][j][0], acc[i][j][1], acc[i][j][2], acc[i][j][3]};
                *(float4*)&out[(((size_t)b * Con + oc) * HOn + ho) * WOn + p0] = v;
            }
    }
}

// ---------------------------------------------------------------------------
extern "C" void kernel_launch(void* const* d_in, const int* in_sizes, int n_in,
                              void* d_out, int out_size, void* d_ws, size_t ws_size,
                              hipStream_t stream) {
    const float* x  = (const float*)d_in[0];   // [8,128,64,64]
    const float* ow = (const float*)d_in[1];   // [54,64,3,3]
    const float* ob = (const float*)d_in[2];   // [54]
    const float* w  = (const float*)d_in[3];   // [128,128,3,3]
    float* out = (float*)d_out;                // [8,128,64,64]

    // ws: wt2 294,912 | owf 73,728 | g_cw 9,437,184 (512 blocks x 18KB)
    unsigned short* wt2 = (unsigned short*)d_ws;
    unsigned short* owf = (unsigned short*)((char*)d_ws + 294912);
    float4*         gcw = (float4*)((char*)d_ws + 294912 + 73728);

    hipLaunchKernelGGL(prep, dim3(720), dim3(256), 0, stream,
                       w, ow, wt2, owf);
    hipLaunchKernelGGL(dcn_fused, dim3(512), dim3(1024), 0, stream,
                       x, owf, ob, wt2, gcw, out);
}

// Round 16
// 111.911 us; speedup vs baseline: 1.0176x; 1.0081x over previous
//
#include <hip/hip_runtime.h>
#include <hip/hip_bf16.h>

// Problem constants
static constexpr int Bn = 8, Cn = 128, Hn = 64, Wn = 64, Con = 128;
static constexpr int KKn = 9, DGn = 2, Cgn = 64;
static constexpr int HOn = 64, WOn = 64;
static constexpr int PITCH = 72;     // bf16 row pitch for s_val rows
static constexpr int OMP3 = 66;      // s_om row pitch (shorts), 64 pos + pad

typedef short short8 __attribute__((ext_vector_type(8)));
typedef float f32x4  __attribute__((ext_vector_type(4)));

__device__ __forceinline__ unsigned short f2bf(float f) {
    unsigned u = __float_as_uint(f);
    u += 0x7fff + ((u >> 16) & 1);          // round-to-nearest-even
    return (unsigned short)(u >> 16);
}
__device__ __forceinline__ float bf2f(unsigned short h) {
    return __uint_as_float(((unsigned)h) << 16);
}

// ---------------------------------------------------------------------------
// Kernel P (R18, proven): WEIGHTS-ONLY prep.
// Blocks [0,576):   main weight -> MFMA B-frag order wt2[gk][ks][tile][lane][8].
// Blocks [576,720): offset weight -> owf[g][ks=tap*2+ch][nt][lane][8].
// ---------------------------------------------------------------------------
__global__ __launch_bounds__(256) void prep(const float* __restrict__ w,
                                            const float* __restrict__ ow,
                                            unsigned short* __restrict__ wt2,
                                            unsigned short* __restrict__ owf) {
    const int blk = blockIdx.x;
    const int t = threadIdx.x;
    if (blk < 576) {
        int e    = blk * 256 + t;                // [0,147456)
        int j    = e & 7;
        int lane = (e >> 3) & 63;
        int tile = (e >> 9) & 7;
        int ks   = (e >> 12) & 1;
        int gk   = e >> 13;                      // 0..17
        int g = gk / 9, k = gk - g * 9;
        int oc = tile * 16 + (lane & 15);
        int c  = ks * 32 + (lane >> 4) * 8 + j;
        wt2[e] = f2bf(w[((size_t)oc * Cn + g * Cgn + c) * KKn + k]);
    } else {
        int e = (blk - 576) * 256 + t;           // [0,36864)
        int g  = e / 18432;
        int r  = e - g * 18432;
        int ks = r >> 10;
        int r2 = r & 1023;
        int nt = r2 >> 9;
        int lane = (r2 >> 3) & 63;
        int j  = r2 & 7;
        int tap = ks >> 1, chalf = ks & 1;
        int oc_l = nt * 16 + (lane & 15);
        int c = chalf * 32 + (lane >> 4) * 8 + j;
        float v = 0.f;
        if (oc_l < 27)
            v = ow[((size_t)(g * 27 + oc_l) * Cgn + c) * KKn + tap];
        owf[e] = f2bf(v);
    }
}

// ---------------------------------------------------------------------------
// Kernel 2 (R24 = R18 verbatim — session-best configuration, total 112.2us).
// Nine structural mechanisms were tested against this kernel's ~47.5us and
// all were null or negative (see session ledger R9-R23): it is latency-
// structure-bound on the data-dependent gather chain (no pipe >45%), and
// the remaining bench time is harness-fixed (42us workspace re-poison fill
// + ~18us launch/reset machinery).
//   - Stage: on-the-fly NCHW->NHWC window (rows ho-3..ho+3, swizzled),
//     x read fp32-coalesced, L3-resident; no separate transpose kernel.
//   - P0: offset-conv on all 16 waves, A-operands from the LDS window.
//   - P1: sampling params (cw/pk) for all 18x64 (gk,pos).
//   - P2: waves 0-7 gather (LDS window fast path, global fallback for
//     out-of-window offsets -> correct for arbitrary inputs); waves 8-15
//     MFMA (rh2 x nt2 tiles); dbuf s_val, one barrier per gk; producer
//     gk+1 overlaps consumer gk.
// LDS: 114688 (s_xw) + 18432 (s_val dbuf, s_om aliased) + 18432 (s_cw)
//      + 4608 (s_pk) = 156160 B -> 1 block/CU, 16 waves.
// ---------------------------------------------------------------------------
__global__ __launch_bounds__(1024, 4) void dcn_fused(const float* __restrict__ x,
                                                     const unsigned short* __restrict__ owf,
                                                     const float* __restrict__ ob,
                                                     const unsigned short* __restrict__ wt2,
                                                     float* __restrict__ out) {
    __shared__ __align__(16) unsigned short s_xw[7 * 64 * 16 * 8];   // 114688 B window
    __shared__ __align__(16) unsigned short s_val[2][64 * PITCH];    // 18432 B dbuf
    __shared__ float4 s_cw[18][64];                                  // 18432 B
    __shared__ int    s_pk[18][64];                                  // 4608 B

    unsigned short* s_om = &s_val[0][0];     // alias: s_om (7128 B) lives pre-P2

    const int t  = threadIdx.x;              // [0,1024)
    const int id = blockIdx.x;               // [0,512)
    const int b  = id & 7;                   // XCD-aware: batch b -> XCD b
    const int ho = id >> 3;                  // full output row

    const int lane = t & 63;
    const int wv   = t >> 6;                 // wave id 0..15
    const int lr   = lane & 15;              // MFMA row/col part
    const int lk   = (lane >> 4) * 8;        // MFMA k offset (shorts)
    const int q    = lane >> 4;              // D row quad

    const int lo = max(0, ho - 3);
    const int hi = min(Hn - 1, ho + 3);
    const int nrows = hi - lo + 1;           // <= 7

    const float* xb4 = x + (size_t)b * Cn * Hn * Wn;   // NCHW batch base
    const short8 zz = {0, 0, 0, 0, 0, 0, 0, 0};

    // ---- S: stage x window rows [lo,hi] into LDS, transposing on the fly ----
    for (int u = t; u < nrows * 1024; u += 1024) {
        int xx = u & 63;
        int kk = (u >> 6) & 15;
        int rs = u >> 10;
        int y  = lo + rs;
        short8 v;
#pragma unroll
        for (int j = 0; j < 8; ++j) {
            float f = xb4[(((size_t)(kk * 8 + j) * Hn) + y) * Wn + xx];
            v[j] = (short)f2bf(f);
        }
        *(short8*)&s_xw[(((rs * 64 + xx) * 16) + (kk ^ (xx & 15))) * 8] = v;
    }
    __syncthreads();

    // ---- P0: offset-conv GEMM on ALL 16 waves, A from LDS window ----
    {
        const int cg = wv >> 3;              // conv/deform group
        const int rh4 = (wv >> 1) & 3;       // row quarter (pos base rh4*16)
        const int nh = wv & 1;               // oc 16-block
        const int oc_l = nh * 16 + lr;
        float bias = (oc_l < 27) ? ob[cg * 27 + oc_l] : 0.f;
        f32x4 oacc = (f32x4){bias, bias, bias, bias};

        const unsigned short* wf = owf + (size_t)cg * 18432;

        for (int tap = 0; tap < 9; ++tap) {
            int ky = tap / 3, kx = tap - ky * 3;
            int y = ho - 2 + 2 * ky;
            if (y < 0 || y >= Hn) continue;  // wave-uniform skip (zero pad)
            int slot = y - lo;               // y in [lo,hi] guaranteed
#pragma unroll
            for (int ch = 0; ch < 2; ++ch) {
                int kssl = tap * 2 + ch;
                short8 bv = *(const short8*)&wf[(size_t)kssl * 1024 + nh * 512 + lane * 8];
                int wo = rh4 * 16 + lr;
                int xc = wo - 2 + 2 * kx;
                bool vx = (xc >= 0) & (xc < Wn);
                int xcc = min(max(xc, 0), Wn - 1);
                int kk  = (cg * 8 + ch * 4 + (lane >> 4)) ^ (xcc & 15);
                short8 av = *(const short8*)&s_xw[(((slot * 64 + xcc) * 16) + kk) * 8];
                av = vx ? av : zz;
                oacc = __builtin_amdgcn_mfma_f32_16x16x32_bf16(av, bv, oacc, 0, 0, 0);
            }
        }
        if (oc_l < 27) {
            int c54 = cg * 27 + oc_l;
#pragma unroll
            for (int r = 0; r < 4; ++r)
                s_om[c54 * OMP3 + rh4 * 16 + q * 4 + r] = f2bf(oacc[r]);
        }
    }
    __syncthreads();

    // ---- P1: sampling params for all (gk, pos) of this row ----
    for (int e = t; e < 18 * 64; e += 1024) {
        int pos = e & 63;
        int wo  = pos;
        int gk  = e >> 6;
        int g  = gk / 9, k = gk - g * 9;
        int ky = k / 3,  kx = k - ky * 3;
        float offy = bf2f(s_om[(g * 18 + k * 2 + 0) * OMP3 + pos]);
        float offx = bf2f(s_om[(g * 18 + k * 2 + 1) * OMP3 + pos]);
        float mk   = bf2f(s_om[(36 + g * 9 + k) * OMP3 + pos]);
        mk = 2.0f / (1.0f + __expf(-mk));

        float py = offy + (float)(ky * 2 + ho - 2);
        float px = offx + (float)(kx * 2 + wo - 2);
        float fy = floorf(py), fx = floorf(px);
        int   y0 = (int)fy,    x0 = (int)fx;
        float wy = py - fy,    wx = px - fx;

        bool vy0 = (y0 >= 0) & (y0 < Hn);
        bool vy1 = (y0 + 1 >= 0) & (y0 + 1 < Hn);
        bool vx0 = (x0 >= 0) & (x0 < Wn);
        bool vx1 = (x0 + 1 >= 0) & (x0 + 1 < Wn);
        float4 cw;
        cw.x = (vy0 & vx0) ? (1.f - wy) * (1.f - wx) * mk : 0.f;
        cw.y = (vy0 & vx1) ? (1.f - wy) * wx * mk : 0.f;
        cw.z = (vy1 & vx0) ? wy * (1.f - wx) * mk : 0.f;
        cw.w = (vy1 & vx1) ? wy * wx * mk : 0.f;

        int y0c = min(max(y0, 0), Hn - 1);
        int y1c = min(max(y0 + 1, 0), Hn - 1);
        int x0c = min(max(x0, 0), Wn - 1);
        int x1c = min(max(x0 + 1, 0), Wn - 1);
        s_cw[gk][pos] = cw;
        s_pk[gk][pos] = y0c | (y1c << 8) | (x0c << 16) | (x1c << 24);
    }
    __syncthreads();   // also fences s_om -> s_val reuse

    // ---- P2: producer/consumer gk loop, one barrier per gk ----
    auto gather_tile = [&](int gkj) {
        const int pos = t >> 3;              // 0..63 (t < 512)
        const int c8  = t & 7;               // 8-ch chunk id
        const int g   = (gkj >= 9) ? 1 : 0;
        float4 cw = s_cw[gkj][pos];
        int pk  = s_pk[gkj][pos];
        int y0c = pk & 255, y1c = (pk >> 8) & 255;
        int x0c = (pk >> 16) & 255, x1c = (pk >> 24) & 255;

        short8 a00, a01, a10, a11;
        bool ok = (y0c >= lo) & (y1c <= hi);
        if (__all(ok)) {
            const int kg = g * 8 + c8;
            a00 = *(const short8*)&s_xw[((((y0c - lo) * 64 + x0c) * 16) + (kg ^ (x0c & 15))) * 8];
            a01 = *(const short8*)&s_xw[((((y0c - lo) * 64 + x1c) * 16) + (kg ^ (x1c & 15))) * 8];
            a10 = *(const short8*)&s_xw[((((y1c - lo) * 64 + x0c) * 16) + (kg ^ (x0c & 15))) * 8];
            a11 = *(const short8*)&s_xw[((((y1c - lo) * 64 + x1c) * 16) + (kg ^ (x1c & 15))) * 8];
        } else {
            // rare fallback (offsets beyond window): read NCHW x directly,
            // f2bf -> values bit-identical to the staged path.
            const float* xc0 = xb4 + (size_t)(g * Cgn + c8 * 8) * Hn * Wn;
#pragma unroll
            for (int j = 0; j < 8; ++j) {
                const float* xj = xc0 + (size_t)j * Hn * Wn;
                a00[j] = (short)f2bf(xj[(size_t)y0c * Wn + x0c]);
                a01[j] = (short)f2bf(xj[(size_t)y0c * Wn + x1c]);
                a10[j] = (short)f2bf(xj[(size_t)y1c * Wn + x0c]);
                a11[j] = (short)f2bf(xj[(size_t)y1c * Wn + x1c]);
            }
        }
        short8 h0;
#pragma unroll
        for (int i = 0; i < 8; ++i) {
            float v = cw.x * bf2f((unsigned short)a00[i]) +
                      cw.y * bf2f((unsigned short)a01[i]) +
                      cw.z * bf2f((unsigned short)a10[i]) +
                      cw.w * bf2f((unsigned short)a11[i]);
            h0[i] = (short)f2bf(v);
        }
        *(short8*)&s_val[gkj & 1][pos * PITCH + c8 * 8] = h0;
    };

    f32x4 acc[2][2];                         // [i = mt in pair][j = oc-16 in pair]
#pragma unroll
    for (int i = 0; i < 2; ++i)
#pragma unroll
        for (int j = 0; j < 2; ++j) acc[i][j] = (f32x4){0.f, 0.f, 0.f, 0.f};

    if (wv < 8) gather_tile(0);              // prologue fill buf0

    const int cid = wv - 8;                  // consumer id 0..7 (wv >= 8)
    const int rh2 = cid >> 2;                // mt pair: rows (rh2*2+i)*16
    const int nt2 = cid & 3;                 // oc-32: tiles nt2*2 + j

    for (int gk = 0; gk < 18; ++gk) {
        __syncthreads();                     // s_val[gk&1] ready for consumers
        if (wv < 8) {
            if (gk < 17) gather_tile(gk + 1);   // fill other buffer concurrently
        } else {
            const unsigned short* wf = wt2 + (size_t)gk * 8192;
#pragma unroll
            for (int ks = 0; ks < 2; ++ks) {
                short8 af[2];
#pragma unroll
                for (int i = 0; i < 2; ++i)
                    af[i] = *(const short8*)&s_val[gk & 1][((rh2 * 2 + i) * 16 + lr) * PITCH + ks * 32 + lk];
#pragma unroll
                for (int i = 0; i < 2; ++i)
#pragma unroll
                    for (int j = 0; j < 2; ++j) {
                        short8 bfr = *(const short8*)&wf[(size_t)(ks * 8 + nt2 * 2 + j) * 512 + lane * 8];
                        acc[i][j] = __builtin_amdgcn_mfma_f32_16x16x32_bf16(af[i], bfr, acc[i][j], 0, 0, 0);
                    }
            }
        }
    }

    // ---- epilogue (consumers): oc = (nt2*2+j)*16 + lr; rows (rh2*2+i)*16 + q*4 ----
    if (wv >= 8) {
#pragma unroll
        for (int i = 0; i < 2; ++i)
#pragma unroll
            for (int j = 0; j < 2; ++j) {
                int oc = (nt2 * 2 + j) * 16 + lr;
                int p0 = (rh2 * 2 + i) * 16 + q * 4;
                float4 v = {acc[i][j][0], acc[i][j][1], acc[i][j][2], acc[i][j][3]};
                *(float4*)&out[(((size_t)b * Con + oc) * HOn + ho) * WOn + p0] = v;
            }
    }
}

// ---------------------------------------------------------------------------
extern "C" void kernel_launch(void* const* d_in, const int* in_sizes, int n_in,
                              void* d_out, int out_size, void* d_ws, size_t ws_size,
                              hipStream_t stream) {
    const float* x  = (const float*)d_in[0];   // [8,128,64,64]
    const float* ow = (const float*)d_in[1];   // [54,64,3,3]
    const float* ob = (const float*)d_in[2];   // [54]
    const float* w  = (const float*)d_in[3];   // [128,128,3,3]
    float* out = (float*)d_out;                // [8,128,64,64]

    // ws: wt2 294,912 | owf 73,728
    unsigned short* wt2 = (unsigned short*)d_ws;
    unsigned short* owf = (unsigned short*)((char*)d_ws + 294912);

    hipLaunchKernelGGL(prep, dim3(720), dim3(256), 0, stream,
                       w, ow, wt2, owf);
    hipLaunchKernelGGL(dcn_fused, dim3(512), dim3(1024), 0, stream,
                       x, owf, ob, wt2, out);
}